// Round 2
// baseline (747.824 us; speedup 1.0000x reference)
//
#include <hip/hip_runtime.h>
#include <math.h>

// ---------------- problem constants (fixed by setup_inputs) ----------------
constexpr int Md   = 2048;      // m
constexpr int NDIM = 784;       // x feature dim
constexpr int DYC  = 10;        // y feature dim
constexpr int MM   = Md * Md;   // 4,194,304 (fits int)
// weighted median ranks: k = 2m^2 - m = 8,386,560 (even)
// targets (0-indexed): k/2-1 and k/2
constexpr unsigned RANK_LO = 4193279u;
constexpr unsigned RANK_HI = 4193280u;
constexpr int NPROB = 12;       // Dx, Dy, 10 components
constexpr int NJOBS = 24;       // 2 ranks per problem

// ---------------- workspace layout (bytes) ----------------
constexpr size_t OFF_DX     = 0;                         // float[MM]  16 MB
constexpr size_t OFF_DY     = OFF_DX + (size_t)MM * 4;   // float[MM]  16 MB
constexpr size_t OFF_RX     = OFF_DY + (size_t)MM * 4;   // double[2048]
constexpr size_t OFF_RY     = OFF_RX + Md * 8;           // double[2048]
constexpr size_t OFF_RC     = OFF_RY + Md * 8;           // double[10*2048]
constexpr size_t OFF_GACC   = OFF_RC + (size_t)DYC * Md * 8;  // double[64]: [0..2]=Gxx,Gxy,Gyy [3..57]=Gc
constexpr size_t OFF_HIST   = OFF_GACC + 64 * 8;         // uint32[24*2048]
constexpr size_t OFF_JOBS   = OFF_HIST + (size_t)NJOBS * 2048 * 4; // uint32[48]: (prefix, rem) per job
constexpr size_t OFF_SELVAL = OFF_JOBS + NJOBS * 8;      // float[24]
constexpr size_t OFF_Q      = OFF_SELVAL + NJOBS * 4;    // float[12]: 2*sigma^2 per problem
constexpr size_t OFF_RXN    = OFF_Q + 12 * 4;            // float[2048] row norms of x
constexpr size_t WS_NEED    = OFF_RXN + Md * 4;
constexpr size_t ZERO_BASE  = OFF_GACC;
constexpr size_t ZERO_LEN   = OFF_RXN - OFF_GACC;        // gacc + hist + jobs + selval + q

// ---------------- helpers ----------------
__device__ __forceinline__ unsigned fkey(float v) {
  unsigned u = __float_as_uint(v);
  return (u & 0x80000000u) ? ~u : (u | 0x80000000u);
}
__device__ __forceinline__ float keyinv(unsigned k) {
  unsigned u = (k & 0x80000000u) ? (k ^ 0x80000000u) : ~k;
  return __uint_as_float(u);
}

// block = 256 threads (4 waves). Result valid on thread 0 only.
__device__ __forceinline__ double blockReduceD(double v) {
  __shared__ double sred[4];
  #pragma unroll
  for (int o = 32; o > 0; o >>= 1) v += __shfl_down(v, o, 64);
  int lane = threadIdx.x & 63;
  int w    = threadIdx.x >> 6;
  __syncthreads();                 // protect sred reuse across calls
  if (lane == 0) sred[w] = v;
  __syncthreads();
  double r = 0.0;
  if (threadIdx.x == 0) { r = sred[0] + sred[1] + sred[2] + sred[3]; }
  return r;
}

// ---------------- kernels ----------------
__global__ void fail_kernel(float* out) { if (threadIdx.x == 0) out[0] = 0.0f; }

__global__ void init_jobs_kernel(unsigned* __restrict__ jobs) {
  int j = threadIdx.x;
  if (j < NJOBS) {
    jobs[j * 2]     = 0u;
    jobs[j * 2 + 1] = (j & 1) ? RANK_HI : RANK_LO;
  }
}

__global__ __launch_bounds__(256) void rownorm_kernel(const float* __restrict__ X,
                                                      float* __restrict__ rxn) {
  int i = blockIdx.x;
  double acc = 0.0;
  for (int k = threadIdx.x; k < NDIM; k += 256) {
    float v = X[i * NDIM + k];
    acc += (double)v * (double)v;
  }
  double r = blockReduceD(acc);
  if (threadIdx.x == 0) rxn[i] = (float)r;
}

// Dx[i,j] = rx[i] + rx[j] - 2*dot(x_i, x_j)   (bitwise symmetric)
__global__ __launch_bounds__(256) void distx_kernel(const float* __restrict__ X,
                                                    const float* __restrict__ rxn,
                                                    float* __restrict__ D) {
  __shared__ float As[16][68];
  __shared__ float Bs[16][68];
  int tid = threadIdx.x;
  int i0 = blockIdx.y * 64, j0 = blockIdx.x * 64;
  int lr = tid >> 2;           // 0..63 tile row
  int lk = (tid & 3) << 2;     // 0,4,8,12 k offset
  int ty = tid >> 4, tx = tid & 15;
  const float* Ar = X + (size_t)(i0 + lr) * NDIM;
  const float* Br = X + (size_t)(j0 + lr) * NDIM;
  float acc[4][4] = {};
  for (int k0 = 0; k0 < NDIM; k0 += 16) {
    float4 av = *(const float4*)(Ar + k0 + lk);
    float4 bv = *(const float4*)(Br + k0 + lk);
    __syncthreads();
    As[lk + 0][lr] = av.x; As[lk + 1][lr] = av.y; As[lk + 2][lr] = av.z; As[lk + 3][lr] = av.w;
    Bs[lk + 0][lr] = bv.x; Bs[lk + 1][lr] = bv.y; Bs[lk + 2][lr] = bv.z; Bs[lk + 3][lr] = bv.w;
    __syncthreads();
    #pragma unroll
    for (int kk = 0; kk < 16; ++kk) {
      float a[4], b[4];
      #pragma unroll
      for (int r = 0; r < 4; ++r) a[r] = As[kk][ty * 4 + r];
      #pragma unroll
      for (int c = 0; c < 4; ++c) b[c] = Bs[kk][tx * 4 + c];
      #pragma unroll
      for (int r = 0; r < 4; ++r)
        #pragma unroll
        for (int c = 0; c < 4; ++c)
          acc[r][c] = fmaf(a[r], b[c], acc[r][c]);
    }
  }
  #pragma unroll
  for (int r = 0; r < 4; ++r) {
    int i = i0 + ty * 4 + r;
    float ri = rxn[i];
    #pragma unroll
    for (int c = 0; c < 4; ++c) {
      int j = j0 + tx * 4 + c;
      float t = ri + rxn[j];                     // symmetric add order
      D[(size_t)i * Md + j] = fmaf(-2.0f, acc[r][c], t);
    }
  }
}

// Dy[i,j] = sum_c (y_ic - y_jc)^2  (bitwise symmetric, more accurate than r-2a+r)
__global__ __launch_bounds__(256) void disty_kernel(const float* __restrict__ Y,
                                                    float* __restrict__ D) {
  __shared__ float Yi[64][10];
  __shared__ float Yj[64][10];
  int i0 = blockIdx.y * 64, j0 = blockIdx.x * 64;
  for (int t = threadIdx.x; t < 640; t += 256) {
    int r = t / 10, c = t % 10;
    Yi[r][c] = Y[(i0 + r) * DYC + c];
    Yj[r][c] = Y[(j0 + r) * DYC + c];
  }
  __syncthreads();
  int jj = threadIdx.x & 63;
  int ii0 = (threadIdx.x >> 6) * 16;
  float yj[10];
  #pragma unroll
  for (int c = 0; c < 10; ++c) yj[c] = Yj[jj][c];
  for (int r = 0; r < 16; ++r) {
    int ii = ii0 + r;
    float s = 0.f;
    #pragma unroll
    for (int c = 0; c < 10; ++c) { float d = Yi[ii][c] - yj[c]; s = fmaf(d, d, s); }
    D[(size_t)(i0 + ii) * Md + (j0 + jj)] = s;
  }
}

// one radix-select histogram pass; grid = (64 blocks, 24 jobs)
__global__ __launch_bounds__(256) void hist_kernel(const float* __restrict__ Dx,
                                                   const float* __restrict__ Dy,
                                                   const float* __restrict__ Y,
                                                   unsigned* __restrict__ hist,
                                                   const unsigned* __restrict__ jobs,
                                                   int level) {
  __shared__ unsigned lh[2048 * 4];    // 4 sub-histograms to cut same-bin LDS-atomic serialization
  __shared__ float ycol[Md];
  int job  = blockIdx.y;
  int prob = job >> 1;
  for (int b = threadIdx.x; b < 2048 * 4; b += 256) lh[b] = 0;
  const float* Mptr = (prob == 0) ? Dx : (prob == 1 ? Dy : nullptr);
  if (prob >= 2) {
    int c = prob - 2;
    for (int i = threadIdx.x; i < Md; i += 256) ycol[i] = Y[i * DYC + c];
  }
  __syncthreads();
  unsigned prefix = jobs[job * 2];
  int start = blockIdx.x * 65536;
  int sub = threadIdx.x & 3;
  for (int t = threadIdx.x; t < 65536; t += 256) {
    int idx = start + t;
    int i = idx >> 11, j = idx & 2047;
    float v;
    if (Mptr) v = Mptr[idx];
    else { float d = ycol[i] - ycol[j]; v = d * d; }
    unsigned key = fkey(v);
    unsigned bin; bool ok;
    if (level == 0)      { ok = true;                      bin = key >> 21; }
    else if (level == 1) { ok = ((key >> 21) == prefix);   bin = (key >> 10) & 2047u; }
    else                 { ok = ((key >> 10) == prefix);   bin = key & 1023u; }
    if (ok) atomicAdd(&lh[bin * 4 + sub], (i == j) ? 1u : 2u);
  }
  __syncthreads();
  unsigned* gh = hist + job * 2048;
  for (int b = threadIdx.x; b < 2048; b += 256) {
    unsigned v = lh[b * 4] + lh[b * 4 + 1] + lh[b * 4 + 2] + lh[b * 4 + 3];
    if (v) atomicAdd(&gh[b], v);
  }
}

// per-job: find bin containing rank, update state, zero hist for next pass
__global__ __launch_bounds__(256) void select_kernel(unsigned* __restrict__ hist,
                                                     unsigned* __restrict__ jobs,
                                                     float* __restrict__ selval,
                                                     int level) {
  __shared__ unsigned lh[2048];
  __shared__ unsigned psum[256];
  int job = blockIdx.x;
  unsigned* gh = hist + job * 2048;
  unsigned s = 0;
  #pragma unroll
  for (int k = 0; k < 8; ++k) {
    unsigned v = gh[threadIdx.x * 8 + k];
    lh[threadIdx.x * 8 + k] = v;
    s += v;
  }
  psum[threadIdx.x] = s;
  __syncthreads();
  if (threadIdx.x == 0) {
    unsigned r = jobs[job * 2 + 1];
    unsigned cum = 0;
    int tseg = 0;
    for (; tseg < 255; ++tseg) { if (cum + psum[tseg] > r) break; cum += psum[tseg]; }
    int b = tseg * 8;
    int bend = b + 7;
    for (; b < bend; ++b) { if (cum + lh[b] > r) break; cum += lh[b]; }  // bounded scan
    unsigned newrem = r - cum;
    unsigned prefix = jobs[job * 2];
    if (level == 0)      { jobs[job * 2] = (unsigned)b; }
    else if (level == 1) { jobs[job * 2] = (prefix << 11) | (unsigned)b; }
    else {
      unsigned key = (prefix << 10) | (unsigned)b;
      selval[job] = keyinv(key);
    }
    jobs[job * 2 + 1] = newrem;
  }
  __syncthreads();
  for (int b = threadIdx.x; b < 2048; b += 256) gh[b] = 0;
}

__global__ void sigma_kernel(const float* __restrict__ selval, float* __restrict__ q) {
  int p = threadIdx.x;
  if (p < NPROB) {
    float med = 0.5f * (selval[2 * p] + selval[2 * p + 1]);  // k even: average the two middles
    med = fmaxf(med, 0.01f);                                 // (med<=0 impossible here: distances >= 0)
    q[p] = 2.0f * med * med;                                 // 2*sigma^2
  }
}

// row sums of E = expm1(-D/q) for Dx and Dy; grid (2048 rows, 2 matrices)
__global__ __launch_bounds__(256) void rowsum_xy_kernel(const float* __restrict__ Dx,
                                                        const float* __restrict__ Dy,
                                                        const float* __restrict__ q,
                                                        double* __restrict__ Rx,
                                                        double* __restrict__ Ry) {
  int z = blockIdx.y;
  const float* Mp = z ? Dy : Dx;
  double* Rp = z ? Ry : Rx;
  float qq = q[z];
  int i = blockIdx.x;
  double acc = 0.0;
  for (int j = threadIdx.x; j < Md; j += 256) {
    float u = Mp[(size_t)i * Md + j] / qq;
    acc += (double)expm1f(-u);
  }
  double r = blockReduceD(acc);
  if (threadIdx.x == 0) Rp[i] = r;
}

// Gxx, Gxy, Gyy = sum_ij Ex*Ex, Ex*Ey, Ey*Ey
__global__ __launch_bounds__(256) void grand_xy_kernel(const float* __restrict__ Dx,
                                                       const float* __restrict__ Dy,
                                                       const float* __restrict__ q,
                                                       double* __restrict__ gacc) {
  float qx = q[0], qy = q[1];
  double gxx = 0, gxy = 0, gyy = 0;
  int stride = gridDim.x * 256;
  for (int idx = blockIdx.x * 256 + threadIdx.x; idx < MM; idx += stride) {
    float ex = expm1f(-(Dx[idx] / qx));
    float ey = expm1f(-(Dy[idx] / qy));
    gxx += (double)ex * ex;
    gxy += (double)ex * ey;
    gyy += (double)ey * ey;
  }
  double r;
  r = blockReduceD(gxx); if (threadIdx.x == 0) atomicAdd(&gacc[0], r);
  r = blockReduceD(gxy); if (threadIdx.x == 0) atomicAdd(&gacc[1], r);
  r = blockReduceD(gyy); if (threadIdx.x == 0) atomicAdd(&gacc[2], r);
}

// per-component row sums Rc[c][i] = sum_j expm1(-(y_ic-y_jc)^2/q_c)
__global__ __launch_bounds__(256) void comp_rowsum_kernel(const float* __restrict__ Y,
                                                          const float* __restrict__ q,
                                                          double* __restrict__ Rc) {
  int i = blockIdx.x;
  float yi[10], qc[10];
  #pragma unroll
  for (int c = 0; c < 10; ++c) { yi[c] = Y[i * DYC + c]; qc[c] = q[2 + c]; }
  double acc[10] = {};
  for (int j = threadIdx.x; j < Md; j += 256) {
    #pragma unroll
    for (int c = 0; c < 10; ++c) {
      float d = yi[c] - Y[j * DYC + c];
      float u = (d * d) / qc[c];
      acc[c] += (double)expm1f(-u);
    }
  }
  for (int c = 0; c < 10; ++c) {
    double r = blockReduceD(acc[c]);
    if (threadIdx.x == 0) Rc[c * Md + i] = r;
  }
}

// Gc[a<=b] = sum_ij E_a[ij]*E_b[ij]  (55 fp64 accumulators per thread)
__global__ __launch_bounds__(256, 2) void comp_grand_kernel(const float* __restrict__ Y,
                                                            const float* __restrict__ q,
                                                            double* __restrict__ gacc) {
  float qc[10];
  #pragma unroll
  for (int c = 0; c < 10; ++c) qc[c] = q[2 + c];
  double acc[55];
  #pragma unroll
  for (int k = 0; k < 55; ++k) acc[k] = 0.0;
  int stride = gridDim.x * 256;
  for (int idx = blockIdx.x * 256 + threadIdx.x; idx < MM; idx += stride) {
    int i = idx >> 11, j = idx & 2047;
    float e[10];
    #pragma unroll
    for (int c = 0; c < 10; ++c) {
      float d = Y[i * DYC + c] - Y[j * DYC + c];
      e[c] = expm1f(-((d * d) / qc[c]));
    }
    int k = 0;
    #pragma unroll
    for (int a = 0; a < 10; ++a)
      #pragma unroll
      for (int b = a; b < 10; ++b) { acc[k] += (double)e[a] * e[b]; ++k; }
  }
  __shared__ double red[55 * 4];
  int lane = threadIdx.x & 63, w = threadIdx.x >> 6;
  #pragma unroll
  for (int k = 0; k < 55; ++k) {
    double v = acc[k];
    #pragma unroll
    for (int o = 32; o > 0; o >>= 1) v += __shfl_down(v, o, 64);
    if (lane == 0) red[k * 4 + w] = v;
  }
  __syncthreads();
  for (int k = threadIdx.x; k < 55; k += 256) {
    double v = red[k * 4] + red[k * 4 + 1] + red[k * 4 + 2] + red[k * 4 + 3];
    atomicAdd(&gacc[3 + k], v);
  }
}

// combine everything: centering identities + final scalar
__global__ __launch_bounds__(256, 1) void final_kernel(const double* __restrict__ Rx,
                                                       const double* __restrict__ Ry,
                                                       const double* __restrict__ Rc,
                                                       const double* __restrict__ gacc,
                                                       float* __restrict__ out) {
  __shared__ double res[73];  // [0..4] sA,sB,sAB,sAA,sBB ; [8..17] TR ; [18..72] RR
  double sA = 0, sB = 0, sAB = 0, sAA = 0, sBB = 0;
  for (int i = threadIdx.x; i < Md; i += 256) {
    double a = Rx[i], b = Ry[i];
    sA += a; sB += b; sAB += a * b; sAA += a * a; sBB += b * b;
  }
  double r;
  r = blockReduceD(sA);  if (threadIdx.x == 0) res[0] = r;
  r = blockReduceD(sB);  if (threadIdx.x == 0) res[1] = r;
  r = blockReduceD(sAB); if (threadIdx.x == 0) res[2] = r;
  r = blockReduceD(sAA); if (threadIdx.x == 0) res[3] = r;
  r = blockReduceD(sBB); if (threadIdx.x == 0) res[4] = r;

  double tr[10], rr[55];
  #pragma unroll
  for (int c = 0; c < 10; ++c) tr[c] = 0.0;
  #pragma unroll
  for (int k = 0; k < 55; ++k) rr[k] = 0.0;
  for (int i = threadIdx.x; i < Md; i += 256) {
    double rc[10];
    #pragma unroll
    for (int c = 0; c < 10; ++c) rc[c] = Rc[c * Md + i];
    #pragma unroll
    for (int c = 0; c < 10; ++c) tr[c] += rc[c];
    int k = 0;
    #pragma unroll
    for (int a = 0; a < 10; ++a)
      #pragma unroll
      for (int b = a; b < 10; ++b) { rr[k] += rc[a] * rc[b]; ++k; }
  }
  for (int c = 0; c < 10; ++c) { r = blockReduceD(tr[c]); if (threadIdx.x == 0) res[8 + c] = r; }
  for (int k = 0; k < 55; ++k) { r = blockReduceD(rr[k]); if (threadIdx.x == 0) res[18 + k] = r; }
  __syncthreads();

  if (threadIdx.x == 0) {
    const double m = (double)Md, m2 = m * m;
    double Gxx = gacc[0], Gxy = gacc[1], Gyy = gacc[2];
    double Sxy = Gxy - (2.0 / m) * res[2] + (res[0] * res[1]) / m2;
    double Sxx = Gxx - (2.0 / m) * res[3] + (res[0] * res[0]) / m2;
    double Syy = Gyy - (2.0 / m) * res[4] + (res[1] * res[1]) / m2;
    double mi_io = Sxy / sqrt(Sxx * Syy);

    double Sc[55], diag[10];
    int k = 0;
    for (int a = 0; a < 10; ++a)
      for (int b = a; b < 10; ++b) {
        double S = gacc[3 + k] - (2.0 / m) * res[18 + k] + (res[8 + a] * res[8 + b]) / m2;
        Sc[k] = S;
        if (a == b) diag[a] = S;
        ++k;
      }
    double comp = 0.0;
    k = 0;
    for (int a = 0; a < 10; ++a)
      for (int b = a; b < 10; ++b) {
        if (b > a) comp += Sc[k] / sqrt(diag[a] * diag[b]);
        ++k;
      }
    out[0] = (float)(-mi_io + comp);
  }
}

// ---------------- launch ----------------
extern "C" void kernel_launch(void* const* d_in, const int* in_sizes, int n_in,
                              void* d_out, int out_size, void* d_ws, size_t ws_size,
                              hipStream_t stream) {
  const float* X = (const float*)d_in[0];
  const float* Y = (const float*)d_in[1];
  float* out = (float*)d_out;
  char* ws = (char*)d_ws;

  // Defensive: never write past the provided workspace (an OOB device write
  // can fault the GPU and kill the container). Degrade to a wrong-but-safe
  // deterministic answer instead.
  if (ws_size < WS_NEED) {
    fail_kernel<<<1, 64, 0, stream>>>(out);
    return;
  }

  float*    Dx     = (float*)(ws + OFF_DX);
  float*    Dy     = (float*)(ws + OFF_DY);
  double*   Rx     = (double*)(ws + OFF_RX);
  double*   Ry     = (double*)(ws + OFF_RY);
  double*   Rc     = (double*)(ws + OFF_RC);
  double*   gacc   = (double*)(ws + OFF_GACC);
  unsigned* hist   = (unsigned*)(ws + OFF_HIST);
  unsigned* jobs   = (unsigned*)(ws + OFF_JOBS);
  float*    selval = (float*)(ws + OFF_SELVAL);
  float*    q      = (float*)(ws + OFF_Q);
  float*    rxn    = (float*)(ws + OFF_RXN);

  hipMemsetAsync(ws + ZERO_BASE, 0, ZERO_LEN, stream);
  init_jobs_kernel<<<1, 32, 0, stream>>>(jobs);

  rownorm_kernel<<<Md, 256, 0, stream>>>(X, rxn);
  distx_kernel<<<dim3(32, 32), 256, 0, stream>>>(X, rxn, Dx);
  disty_kernel<<<dim3(32, 32), 256, 0, stream>>>(Y, Dy);

  for (int lvl = 0; lvl < 3; ++lvl) {
    hist_kernel<<<dim3(64, NJOBS), 256, 0, stream>>>(Dx, Dy, Y, hist, jobs, lvl);
    select_kernel<<<NJOBS, 256, 0, stream>>>(hist, jobs, selval, lvl);
  }
  sigma_kernel<<<1, 32, 0, stream>>>(selval, q);

  rowsum_xy_kernel<<<dim3(Md, 2), 256, 0, stream>>>(Dx, Dy, q, Rx, Ry);
  grand_xy_kernel<<<512, 256, 0, stream>>>(Dx, Dy, q, gacc);
  comp_rowsum_kernel<<<Md, 256, 0, stream>>>(Y, q, Rc);
  comp_grand_kernel<<<512, 256, 0, stream>>>(Y, q, gacc);
  final_kernel<<<1, 256, 0, stream>>>(Rx, Ry, Rc, gacc, out);
}

// Round 3
// 618.472 us; speedup vs baseline: 1.2091x; 1.2091x over previous
//
#include <hip/hip_runtime.h>
#include <math.h>

// ---------------- problem constants (fixed by setup_inputs) ----------------
constexpr int Md   = 2048;      // m
constexpr int NDIM = 784;       // x feature dim
constexpr int DYC  = 10;        // y feature dim
constexpr int MM   = Md * Md;   // 4,194,304 (fits int)
// weighted median: multiset = full D (m^2, weight per (i,j)) + 2x strict tril.
// Per unordered pair i<j: weight 4; diagonal: weight 1. k = 2m^2 - m = 8,386,560 (even).
constexpr unsigned RANK_LO = 4193279u;  // k/2-1 (0-indexed)
constexpr unsigned RANK_HI = 4193280u;  // k/2
constexpr int NPROB = 12;       // Dx, Dy, 10 components
constexpr int NB    = 128;      // blocks per problem in scan kernels
constexpr int NBINS = 8192;     // 13-bit histogram levels (13/13/6 split)

// ---------------- workspace layout (bytes) ----------------
constexpr size_t OFF_DX     = 0;                         // float[MM]  16 MB
constexpr size_t OFF_DY     = OFF_DX + (size_t)MM * 4;   // float[MM]  16 MB
constexpr size_t OFF_RX     = OFF_DY + (size_t)MM * 4;   // double[2048]
constexpr size_t OFF_RY     = OFF_RX + Md * 8;           // double[2048]
constexpr size_t OFF_RC     = OFF_RY + Md * 8;           // double[10*2048]
constexpr size_t OFF_GACC   = OFF_RC + (size_t)DYC * Md * 8;  // double[64]
constexpr size_t OFF_HIST   = OFF_GACC + 64 * 8;         // uint32[12*8192]
constexpr size_t OFF_JOBS   = OFF_HIST + (size_t)NPROB * NBINS * 4; // uint32[24]
constexpr size_t OFF_SELKEY = OFF_JOBS + NPROB * 8;      // uint32[12]
constexpr size_t OFF_CNTLE  = OFF_SELKEY + NPROB * 4;    // uint32[12]
constexpr size_t OFF_MINAB  = OFF_CNTLE + NPROB * 4;     // uint32[12]
constexpr size_t OFF_Q      = OFF_MINAB + NPROB * 4;     // float[12]: 2*sigma^2
constexpr size_t OFF_RXN    = OFF_Q + NPROB * 4;         // float[2048]
constexpr size_t WS_NEED    = OFF_RXN + Md * 4;
constexpr size_t ZERO_BASE  = OFF_GACC;
constexpr size_t ZERO_LEN   = OFF_JOBS - OFF_GACC;       // gacc + hist

// ---------------- helpers ----------------
__device__ __forceinline__ unsigned fkey(float v) {
  unsigned u = __float_as_uint(v);
  return (u & 0x80000000u) ? ~u : (u | 0x80000000u);
}
__device__ __forceinline__ float keyinv(unsigned k) {
  unsigned u = (k & 0x80000000u) ? (k ^ 0x80000000u) : ~k;
  return __uint_as_float(u);
}

// block = 256 threads (4 waves). Result valid on thread 0 only.
__device__ __forceinline__ double blockReduceD(double v) {
  __shared__ double sred[4];
  #pragma unroll
  for (int o = 32; o > 0; o >>= 1) v += __shfl_down(v, o, 64);
  int lane = threadIdx.x & 63;
  int w    = threadIdx.x >> 6;
  __syncthreads();
  if (lane == 0) sred[w] = v;
  __syncthreads();
  double r = 0.0;
  if (threadIdx.x == 0) { r = sred[0] + sred[1] + sred[2] + sred[3]; }
  return r;
}

// ---------------- kernels ----------------
__global__ void fail_kernel(float* out) { if (threadIdx.x == 0) out[0] = 0.0f; }

__global__ void init_misc_kernel(unsigned* __restrict__ jobs,
                                 unsigned* __restrict__ cntle,
                                 unsigned* __restrict__ minab) {
  int p = threadIdx.x;
  if (p < NPROB) {
    jobs[p * 2]     = 0u;
    jobs[p * 2 + 1] = RANK_LO;
    cntle[p] = 0u;
    minab[p] = 0xFFFFFFFFu;
  }
}

__global__ __launch_bounds__(256) void rownorm_kernel(const float* __restrict__ X,
                                                      float* __restrict__ rxn) {
  int i = blockIdx.x;
  double acc = 0.0;
  for (int k = threadIdx.x; k < NDIM; k += 256) {
    float v = X[i * NDIM + k];
    acc += (double)v * (double)v;
  }
  double r = blockReduceD(acc);
  if (threadIdx.x == 0) rxn[i] = (float)r;
}

// Dx[i,j] = rx[i] + rx[j] - 2*dot(x_i, x_j)   (bitwise symmetric)
__global__ __launch_bounds__(256) void distx_kernel(const float* __restrict__ X,
                                                    const float* __restrict__ rxn,
                                                    float* __restrict__ D) {
  __shared__ float As[16][68];
  __shared__ float Bs[16][68];
  int tid = threadIdx.x;
  int i0 = blockIdx.y * 64, j0 = blockIdx.x * 64;
  int lr = tid >> 2;
  int lk = (tid & 3) << 2;
  int ty = tid >> 4, tx = tid & 15;
  const float* Ar = X + (size_t)(i0 + lr) * NDIM;
  const float* Br = X + (size_t)(j0 + lr) * NDIM;
  float acc[4][4] = {};
  for (int k0 = 0; k0 < NDIM; k0 += 16) {
    float4 av = *(const float4*)(Ar + k0 + lk);
    float4 bv = *(const float4*)(Br + k0 + lk);
    __syncthreads();
    As[lk + 0][lr] = av.x; As[lk + 1][lr] = av.y; As[lk + 2][lr] = av.z; As[lk + 3][lr] = av.w;
    Bs[lk + 0][lr] = bv.x; Bs[lk + 1][lr] = bv.y; Bs[lk + 2][lr] = bv.z; Bs[lk + 3][lr] = bv.w;
    __syncthreads();
    #pragma unroll
    for (int kk = 0; kk < 16; ++kk) {
      float a[4], b[4];
      #pragma unroll
      for (int r = 0; r < 4; ++r) a[r] = As[kk][ty * 4 + r];
      #pragma unroll
      for (int c = 0; c < 4; ++c) b[c] = Bs[kk][tx * 4 + c];
      #pragma unroll
      for (int r = 0; r < 4; ++r)
        #pragma unroll
        for (int c = 0; c < 4; ++c)
          acc[r][c] = fmaf(a[r], b[c], acc[r][c]);
    }
  }
  #pragma unroll
  for (int r = 0; r < 4; ++r) {
    int i = i0 + ty * 4 + r;
    float ri = rxn[i];
    #pragma unroll
    for (int c = 0; c < 4; ++c) {
      int j = j0 + tx * 4 + c;
      float t = ri + rxn[j];
      D[(size_t)i * Md + j] = fmaf(-2.0f, acc[r][c], t);
    }
  }
}

// Dy[i,j] = sum_c (y_ic - y_jc)^2  (bitwise symmetric)
__global__ __launch_bounds__(256) void disty_kernel(const float* __restrict__ Y,
                                                    float* __restrict__ D) {
  __shared__ float Yi[64][10];
  __shared__ float Yj[64][10];
  int i0 = blockIdx.y * 64, j0 = blockIdx.x * 64;
  for (int t = threadIdx.x; t < 640; t += 256) {
    int r = t / 10, c = t % 10;
    Yi[r][c] = Y[(i0 + r) * DYC + c];
    Yj[r][c] = Y[(j0 + r) * DYC + c];
  }
  __syncthreads();
  int jj = threadIdx.x & 63;
  int ii0 = (threadIdx.x >> 6) * 16;
  float yj[10];
  #pragma unroll
  for (int c = 0; c < 10; ++c) yj[c] = Yj[jj][c];
  for (int r = 0; r < 16; ++r) {
    int ii = ii0 + r;
    float s = 0.f;
    #pragma unroll
    for (int c = 0; c < 10; ++c) { float d = Yi[ii][c] - yj[c]; s = fmaf(d, d, s); }
    D[(size_t)(i0 + ii) * Md + (j0 + jj)] = s;
  }
}

// one radix-select histogram pass over the lower triangle (weight 4 off-diag, 1 diag).
// grid = (NB, 12 problems). Levels: 13 bits [31:19], 13 bits [18:6], 6 bits [5:0].
__global__ __launch_bounds__(256) void hist_kernel(const float* __restrict__ Dx,
                                                   const float* __restrict__ Dy,
                                                   const float* __restrict__ Y,
                                                   unsigned* __restrict__ hist,
                                                   const unsigned* __restrict__ jobs,
                                                   int level) {
  __shared__ unsigned lh[NBINS];   // 32 KB
  __shared__ float ycol[Md];       // 8 KB
  int prob = blockIdx.y;
  for (int b = threadIdx.x; b < NBINS; b += 256) lh[b] = 0;
  const float* Mptr = (prob == 0) ? Dx : (prob == 1 ? Dy : nullptr);
  if (prob >= 2) {
    int c = prob - 2;
    for (int i = threadIdx.x; i < Md; i += 256) ycol[i] = Y[i * DYC + c];
  }
  __syncthreads();
  unsigned prefix = jobs[prob * 2];
  for (int r = 0; r < Md / NB; ++r) {
    int i = blockIdx.x + r * NB;   // interleaved rows for load balance
    const float* row = Mptr ? (Mptr + (size_t)i * Md) : nullptr;
    float yi = Mptr ? 0.f : ycol[i];
    for (int j = threadIdx.x; j <= i; j += 256) {
      float v;
      if (Mptr) v = row[j];
      else { float d = yi - ycol[j]; v = d * d; }
      unsigned key = fkey(v);
      unsigned bin; bool ok;
      if (level == 0)      { ok = true;                    bin = key >> 19; }
      else if (level == 1) { ok = ((key >> 19) == prefix); bin = (key >> 6) & 8191u; }
      else                 { ok = ((key >> 6) == prefix);  bin = key & 63u; }
      if (ok) atomicAdd(&lh[bin], (j == i) ? 1u : 4u);
    }
  }
  __syncthreads();
  unsigned* gh = hist + prob * NBINS;
  for (int b = threadIdx.x; b < NBINS; b += 256) {
    unsigned v = lh[b];
    if (v) atomicAdd(&gh[b], v);
  }
}

// per-problem: find bin containing rank, update state, zero hist for next pass
__global__ __launch_bounds__(256) void select_kernel(unsigned* __restrict__ hist,
                                                     unsigned* __restrict__ jobs,
                                                     unsigned* __restrict__ selkey,
                                                     int level) {
  __shared__ unsigned lh[NBINS];
  __shared__ unsigned psum[256];
  int job = blockIdx.x;
  int nbins = (level == 2) ? 64 : NBINS;
  int C = (nbins + 255) / 256;     // 32 or 1
  unsigned* gh = hist + job * NBINS;
  unsigned s = 0;
  for (int k = 0; k < C; ++k) {
    int b = threadIdx.x * C + k;
    if (b < nbins) { unsigned v = gh[b]; lh[b] = v; s += v; }
  }
  psum[threadIdx.x] = s;
  __syncthreads();
  if (threadIdx.x == 0) {
    unsigned r = jobs[job * 2 + 1];
    unsigned cum = 0;
    int t = 0;
    for (; t < 255; ++t) { if (cum + psum[t] > r) break; cum += psum[t]; }
    int b = t * C;
    int bend = b + C - 1;
    if (bend > nbins - 1) bend = nbins - 1;
    for (; b < bend; ++b) { if (cum + lh[b] > r) break; cum += lh[b]; }  // bounded
    unsigned prefix = jobs[job * 2];
    if (level == 0)      { jobs[job * 2] = (unsigned)b; }
    else if (level == 1) { jobs[job * 2] = (prefix << 13) | (unsigned)b; }
    else                 { selkey[job] = (prefix << 6) | (unsigned)b; }
    jobs[job * 2 + 1] = r - cum;
  }
  __syncthreads();
  for (int b = threadIdx.x; b < nbins; b += 256) gh[b] = 0;
}

// one pass: C_le = weighted count(key <= K_lo), minAbove = min key > K_lo
__global__ __launch_bounds__(256) void countle_kernel(const float* __restrict__ Dx,
                                                      const float* __restrict__ Dy,
                                                      const float* __restrict__ Y,
                                                      const unsigned* __restrict__ selkey,
                                                      unsigned* __restrict__ cntle,
                                                      unsigned* __restrict__ minab) {
  __shared__ float ycol[Md];
  __shared__ unsigned scnt[4], smin[4];
  int prob = blockIdx.y;
  const float* Mptr = (prob == 0) ? Dx : (prob == 1 ? Dy : nullptr);
  if (prob >= 2) {
    int c = prob - 2;
    for (int i = threadIdx.x; i < Md; i += 256) ycol[i] = Y[i * DYC + c];
  }
  __syncthreads();
  unsigned K = selkey[prob];
  unsigned cnt = 0, mn = 0xFFFFFFFFu;
  for (int r = 0; r < Md / NB; ++r) {
    int i = blockIdx.x + r * NB;
    const float* row = Mptr ? (Mptr + (size_t)i * Md) : nullptr;
    float yi = Mptr ? 0.f : ycol[i];
    for (int j = threadIdx.x; j <= i; j += 256) {
      float v;
      if (Mptr) v = row[j];
      else { float d = yi - ycol[j]; v = d * d; }
      unsigned key = fkey(v);
      if (key <= K) cnt += (j == i) ? 1u : 4u;
      else if (key < mn) mn = key;
    }
  }
  #pragma unroll
  for (int o = 32; o > 0; o >>= 1) {
    cnt += __shfl_down(cnt, o, 64);
    unsigned m2 = __shfl_down(mn, o, 64);
    if (m2 < mn) mn = m2;
  }
  int lane = threadIdx.x & 63, w = threadIdx.x >> 6;
  if (lane == 0) { scnt[w] = cnt; smin[w] = mn; }
  __syncthreads();
  if (threadIdx.x == 0) {
    unsigned c = scnt[0] + scnt[1] + scnt[2] + scnt[3];
    unsigned m = min(min(smin[0], smin[1]), min(smin[2], smin[3]));
    atomicAdd(&cntle[prob], c);
    atomicMin(&minab[prob], m);
  }
}

__global__ void sigma2_kernel(const unsigned* __restrict__ selkey,
                              const unsigned* __restrict__ cntle,
                              const unsigned* __restrict__ minab,
                              float* __restrict__ q) {
  int p = threadIdx.x;
  if (p < NPROB) {
    float vlo = keyinv(selkey[p]);
    float vhi = (cntle[p] > RANK_HI) ? vlo : keyinv(minab[p]);
    float med = 0.5f * (vlo + vhi);
    med = fmaxf(med, 0.01f);
    q[p] = 2.0f * med * med;    // 2*sigma^2
  }
}

// fused: row sums of E=expm1(-D/q) for Dx,Dy AND Gxx,Gxy,Gyy in one pass
__global__ __launch_bounds__(256) void rowgrand_kernel(const float* __restrict__ Dx,
                                                       const float* __restrict__ Dy,
                                                       const float* __restrict__ q,
                                                       double* __restrict__ Rx,
                                                       double* __restrict__ Ry,
                                                       double* __restrict__ gacc) {
  int i = blockIdx.x;
  float qx = q[0], qy = q[1];
  const float* rowx = Dx + (size_t)i * Md;
  const float* rowy = Dy + (size_t)i * Md;
  double ax = 0, ay = 0, gxx = 0, gxy = 0, gyy = 0;
  for (int j = threadIdx.x; j < Md; j += 256) {
    float ex = expm1f(-(rowx[j] / qx));
    float ey = expm1f(-(rowy[j] / qy));
    ax += (double)ex; ay += (double)ey;
    gxx += (double)ex * ex;
    gxy += (double)ex * ey;
    gyy += (double)ey * ey;
  }
  double r;
  r = blockReduceD(ax);  if (threadIdx.x == 0) Rx[i] = r;
  r = blockReduceD(ay);  if (threadIdx.x == 0) Ry[i] = r;
  r = blockReduceD(gxx); if (threadIdx.x == 0) atomicAdd(&gacc[0], r);
  r = blockReduceD(gxy); if (threadIdx.x == 0) atomicAdd(&gacc[1], r);
  r = blockReduceD(gyy); if (threadIdx.x == 0) atomicAdd(&gacc[2], r);
}

// per-component row sums Rc[c][i] = sum_j expm1(-(y_ic-y_jc)^2/q_c)
__global__ __launch_bounds__(256) void comp_rowsum_kernel(const float* __restrict__ Y,
                                                          const float* __restrict__ q,
                                                          double* __restrict__ Rc) {
  int i = blockIdx.x;
  float yi[10], qc[10];
  #pragma unroll
  for (int c = 0; c < 10; ++c) { yi[c] = Y[i * DYC + c]; qc[c] = q[2 + c]; }
  double acc[10] = {};
  for (int j = threadIdx.x; j < Md; j += 256) {
    #pragma unroll
    for (int c = 0; c < 10; ++c) {
      float d = yi[c] - Y[j * DYC + c];
      float u = (d * d) / qc[c];
      acc[c] += (double)expm1f(-u);
    }
  }
  for (int c = 0; c < 10; ++c) {
    double r = blockReduceD(acc[c]);
    if (threadIdx.x == 0) Rc[c * Md + i] = r;
  }
}

// Gc[a<=b] = sum_ij E_a[ij]*E_b[ij]  (55 fp64 accumulators per thread)
__global__ __launch_bounds__(256, 2) void comp_grand_kernel(const float* __restrict__ Y,
                                                            const float* __restrict__ q,
                                                            double* __restrict__ gacc) {
  float qc[10];
  #pragma unroll
  for (int c = 0; c < 10; ++c) qc[c] = q[2 + c];
  double acc[55];
  #pragma unroll
  for (int k = 0; k < 55; ++k) acc[k] = 0.0;
  int stride = gridDim.x * 256;
  for (int idx = blockIdx.x * 256 + threadIdx.x; idx < MM; idx += stride) {
    int i = idx >> 11, j = idx & 2047;
    float e[10];
    #pragma unroll
    for (int c = 0; c < 10; ++c) {
      float d = Y[i * DYC + c] - Y[j * DYC + c];
      e[c] = expm1f(-((d * d) / qc[c]));
    }
    int k = 0;
    #pragma unroll
    for (int a = 0; a < 10; ++a)
      #pragma unroll
      for (int b = a; b < 10; ++b) { acc[k] += (double)e[a] * e[b]; ++k; }
  }
  __shared__ double red[55 * 4];
  int lane = threadIdx.x & 63, w = threadIdx.x >> 6;
  #pragma unroll
  for (int k = 0; k < 55; ++k) {
    double v = acc[k];
    #pragma unroll
    for (int o = 32; o > 0; o >>= 1) v += __shfl_down(v, o, 64);
    if (lane == 0) red[k * 4 + w] = v;
  }
  __syncthreads();
  for (int k = threadIdx.x; k < 55; k += 256) {
    double v = red[k * 4] + red[k * 4 + 1] + red[k * 4 + 2] + red[k * 4 + 3];
    atomicAdd(&gacc[3 + k], v);
  }
}

// combine everything: centering identities + final scalar
__global__ __launch_bounds__(256, 1) void final_kernel(const double* __restrict__ Rx,
                                                       const double* __restrict__ Ry,
                                                       const double* __restrict__ Rc,
                                                       const double* __restrict__ gacc,
                                                       float* __restrict__ out) {
  __shared__ double res[73];
  double sA = 0, sB = 0, sAB = 0, sAA = 0, sBB = 0;
  for (int i = threadIdx.x; i < Md; i += 256) {
    double a = Rx[i], b = Ry[i];
    sA += a; sB += b; sAB += a * b; sAA += a * a; sBB += b * b;
  }
  double r;
  r = blockReduceD(sA);  if (threadIdx.x == 0) res[0] = r;
  r = blockReduceD(sB);  if (threadIdx.x == 0) res[1] = r;
  r = blockReduceD(sAB); if (threadIdx.x == 0) res[2] = r;
  r = blockReduceD(sAA); if (threadIdx.x == 0) res[3] = r;
  r = blockReduceD(sBB); if (threadIdx.x == 0) res[4] = r;

  double tr[10], rr[55];
  #pragma unroll
  for (int c = 0; c < 10; ++c) tr[c] = 0.0;
  #pragma unroll
  for (int k = 0; k < 55; ++k) rr[k] = 0.0;
  for (int i = threadIdx.x; i < Md; i += 256) {
    double rc[10];
    #pragma unroll
    for (int c = 0; c < 10; ++c) rc[c] = Rc[c * Md + i];
    #pragma unroll
    for (int c = 0; c < 10; ++c) tr[c] += rc[c];
    int k = 0;
    #pragma unroll
    for (int a = 0; a < 10; ++a)
      #pragma unroll
      for (int b = a; b < 10; ++b) { rr[k] += rc[a] * rc[b]; ++k; }
  }
  for (int c = 0; c < 10; ++c) { r = blockReduceD(tr[c]); if (threadIdx.x == 0) res[8 + c] = r; }
  for (int k = 0; k < 55; ++k) { r = blockReduceD(rr[k]); if (threadIdx.x == 0) res[18 + k] = r; }
  __syncthreads();

  if (threadIdx.x == 0) {
    const double m = (double)Md, m2 = m * m;
    double Gxx = gacc[0], Gxy = gacc[1], Gyy = gacc[2];
    double Sxy = Gxy - (2.0 / m) * res[2] + (res[0] * res[1]) / m2;
    double Sxx = Gxx - (2.0 / m) * res[3] + (res[0] * res[0]) / m2;
    double Syy = Gyy - (2.0 / m) * res[4] + (res[1] * res[1]) / m2;
    double mi_io = Sxy / sqrt(Sxx * Syy);

    double Sc[55], diag[10];
    int k = 0;
    for (int a = 0; a < 10; ++a)
      for (int b = a; b < 10; ++b) {
        double S = gacc[3 + k] - (2.0 / m) * res[18 + k] + (res[8 + a] * res[8 + b]) / m2;
        Sc[k] = S;
        if (a == b) diag[a] = S;
        ++k;
      }
    double comp = 0.0;
    k = 0;
    for (int a = 0; a < 10; ++a)
      for (int b = a; b < 10; ++b) {
        if (b > a) comp += Sc[k] / sqrt(diag[a] * diag[b]);
        ++k;
      }
    out[0] = (float)(-mi_io + comp);
  }
}

// ---------------- launch ----------------
extern "C" void kernel_launch(void* const* d_in, const int* in_sizes, int n_in,
                              void* d_out, int out_size, void* d_ws, size_t ws_size,
                              hipStream_t stream) {
  const float* X = (const float*)d_in[0];
  const float* Y = (const float*)d_in[1];
  float* out = (float*)d_out;
  char* ws = (char*)d_ws;

  if (ws_size < WS_NEED) {
    fail_kernel<<<1, 64, 0, stream>>>(out);
    return;
  }

  float*    Dx     = (float*)(ws + OFF_DX);
  float*    Dy     = (float*)(ws + OFF_DY);
  double*   Rx     = (double*)(ws + OFF_RX);
  double*   Ry     = (double*)(ws + OFF_RY);
  double*   Rc     = (double*)(ws + OFF_RC);
  double*   gacc   = (double*)(ws + OFF_GACC);
  unsigned* hist   = (unsigned*)(ws + OFF_HIST);
  unsigned* jobs   = (unsigned*)(ws + OFF_JOBS);
  unsigned* selkey = (unsigned*)(ws + OFF_SELKEY);
  unsigned* cntle  = (unsigned*)(ws + OFF_CNTLE);
  unsigned* minab  = (unsigned*)(ws + OFF_MINAB);
  float*    q      = (float*)(ws + OFF_Q);
  float*    rxn    = (float*)(ws + OFF_RXN);

  hipMemsetAsync(ws + ZERO_BASE, 0, ZERO_LEN, stream);
  init_misc_kernel<<<1, 32, 0, stream>>>(jobs, cntle, minab);

  rownorm_kernel<<<Md, 256, 0, stream>>>(X, rxn);
  distx_kernel<<<dim3(32, 32), 256, 0, stream>>>(X, rxn, Dx);
  disty_kernel<<<dim3(32, 32), 256, 0, stream>>>(Y, Dy);

  for (int lvl = 0; lvl < 3; ++lvl) {
    hist_kernel<<<dim3(NB, NPROB), 256, 0, stream>>>(Dx, Dy, Y, hist, jobs, lvl);
    select_kernel<<<NPROB, 256, 0, stream>>>(hist, jobs, selkey, lvl);
  }
  countle_kernel<<<dim3(NB, NPROB), 256, 0, stream>>>(Dx, Dy, Y, selkey, cntle, minab);
  sigma2_kernel<<<1, 32, 0, stream>>>(selkey, cntle, minab, q);

  rowgrand_kernel<<<Md, 256, 0, stream>>>(Dx, Dy, q, Rx, Ry, gacc);
  comp_rowsum_kernel<<<Md, 256, 0, stream>>>(Y, q, Rc);
  comp_grand_kernel<<<512, 256, 0, stream>>>(Y, q, gacc);
  final_kernel<<<1, 256, 0, stream>>>(Rx, Ry, Rc, gacc, out);
}